// Round 2
// baseline (1190.918 us; speedup 1.0000x reference)
//
#include <hip/hip_runtime.h>

typedef __attribute__((ext_vector_type(8))) __bf16 bf16x8;
typedef __attribute__((ext_vector_type(4))) float f32x4;

#define MFMA16(a, b, c) __builtin_amdgcn_mfma_f32_16x16x32_bf16((a), (b), (c), 0, 0, 0)

constexpr int S_LEN = 2048;
constexpr int DIM   = 64;
constexpr int QT    = 16;   // q rows per block
constexpr int KT    = 64;   // k rows per tile (16 cols per wave x 4 waves)
constexpr int NBH   = 32;   // B*H
constexpr float SH  = 14.426950408889634f;  // 10 * log2(e); score*log2e shift

// ---------------- prep 1: normalized K rows -> split bf16 (row-major) --------
__global__ void kprep_kernel(const float* __restrict__ kg,
                             __bf16* __restrict__ khi, __bf16* __restrict__ klo) {
    int row  = (blockIdx.x * blockDim.x + threadIdx.x) >> 6;  // one wave per row
    int lane = threadIdx.x & 63;
    size_t idx = (size_t)row * DIM + lane;
    float x  = kg[idx];
    float ss = x * x;
#pragma unroll
    for (int off = 1; off < 64; off <<= 1) ss += __shfl_xor(ss, off);
    float ik = 1.0f / fmaxf(sqrtf(ss), 1e-12f);
    float xn = x * ik;
    __bf16 h = (__bf16)xn;
    khi[idx] = h;
    klo[idx] = (__bf16)(xn - (float)h);
}

// ---------------- prep 2: V transposed [D][S] -> split bf16 ------------------
__global__ void vtprep_kernel(const float* __restrict__ vg,
                              __bf16* __restrict__ vthi, __bf16* __restrict__ vtlo) {
    __shared__ float ls[64 * 68];
    const int bh = blockIdx.y, kt = blockIdx.x * 64;
    const int tid = threadIdx.x;
    const float4* src = (const float4*)(vg + (size_t)bh * S_LEN * DIM + (size_t)kt * DIM);
#pragma unroll
    for (int e = 0; e < 4; ++e) {
        int f = tid + 256 * e;
        int r = f >> 4, c4 = f & 15;
        float4 val = src[r * 16 + c4];
        float* d = &ls[r * 68 + c4 * 4];
        d[0] = val.x; d[1] = val.y; d[2] = val.z; d[3] = val.w;
    }
    __syncthreads();
    const int d = tid >> 2, seg = tid & 3;
    bf16x8 h0, h1, l0, l1;
#pragma unroll
    for (int j = 0; j < 8; ++j) {
        float x = ls[(seg * 16 + j) * 68 + d];
        __bf16 h = (__bf16)x;
        h0[j] = h; l0[j] = (__bf16)(x - (float)h);
        x = ls[(seg * 16 + 8 + j) * 68 + d];
        h = (__bf16)x;
        h1[j] = h; l1[j] = (__bf16)(x - (float)h);
    }
    size_t ob = (size_t)bh * S_LEN * DIM + (size_t)d * S_LEN + kt + seg * 16;
    *(bf16x8*)(vthi + ob)     = h0;
    *(bf16x8*)(vthi + ob + 8) = h1;
    *(bf16x8*)(vtlo + ob)     = l0;
    *(bf16x8*)(vtlo + ob + 8) = l1;
}

// QK^T 16x64 sub-tile for one wave, from precomputed split-bf16 K rows.
__device__ __forceinline__ f32x4 qk_tile(const __bf16* __restrict__ kh,
                                         const __bf16* __restrict__ kl,
                                         const bf16x8* aqh, const bf16x8* aql, int quad) {
    f32x4 a0 = {0.f, 0.f, 0.f, 0.f}, a1 = {0.f, 0.f, 0.f, 0.f};
    bf16x8 bh0 = *(const bf16x8*)(kh + quad * 8);
    bf16x8 bl0 = *(const bf16x8*)(kl + quad * 8);
    bf16x8 bh1 = *(const bf16x8*)(kh + 32 + quad * 8);
    bf16x8 bl1 = *(const bf16x8*)(kl + 32 + quad * 8);
    a0 = MFMA16(aqh[0], bh0, a0);
    a1 = MFMA16(aqh[1], bh1, a1);
    a0 = MFMA16(aqh[0], bl0, a0);
    a1 = MFMA16(aqh[1], bl1, a1);
    a0 = MFMA16(aql[0], bh0, a0);
    a1 = MFMA16(aql[1], bh1, a1);
    return a0 + a1;
}

// ---------------- main fused attention kernel ----------------
__global__ __launch_bounds__(256, 4)
void attn_kernel(const float* __restrict__ qg,
                 const __bf16* __restrict__ khi, const __bf16* __restrict__ klo,
                 const __bf16* __restrict__ vthi, const __bf16* __restrict__ vtlo,
                 float* __restrict__ outg, float* __restrict__ scoreg) {
    __shared__ float pstage[QT * 68];
    __shared__ float sinvq[QT];
    __shared__ float sinvl[QT];
    __shared__ float redbuf[4][QT];

    const int bh   = blockIdx.y;
    const int q0   = blockIdx.x * QT;
    const int tid  = threadIdx.x;
    const int lane = tid & 63;
    const int wv   = tid >> 6;
    const int quad = lane >> 4;
    const int l16  = lane & 15;

    const size_t hbase = (size_t)bh * S_LEN * DIM;
    const __bf16* kb  = khi  + hbase;
    const __bf16* klb = klo  + hbase;
    const __bf16* vtb  = vthi + hbase;
    const __bf16* vtlb = vtlo + hbase;

    // q-row inverse norms, folded with 10*log2(e)
    {
        int row = tid >> 4, c = tid & 15;
        const float* p = qg + hbase + (size_t)(q0 + row) * DIM;
        float ss = 0.f;
#pragma unroll
        for (int j = 0; j < 4; ++j) { float x = p[c + 16 * j]; ss += x * x; }
#pragma unroll
        for (int off = 1; off < 16; off <<= 1) ss += __shfl_xor(ss, off);
        if (c == 0) sinvq[row] = SH / fmaxf(sqrtf(ss), 1e-12f);
    }
    __syncthreads();

    // Q A-fragments (m = l16, k = quad*8 + j), split hi/lo
    bf16x8 aqh[2], aql[2];
    {
        const float* qr = qg + hbase + (size_t)(q0 + l16) * DIM;
        float iq = sinvq[l16];
#pragma unroll
        for (int ks = 0; ks < 2; ++ks) {
            const float* p = qr + ks * 32 + quad * 8;
            float4 x0 = *(const float4*)(p);
            float4 x1 = *(const float4*)(p + 4);
            float xs[8] = {x0.x, x0.y, x0.z, x0.w, x1.x, x1.y, x1.z, x1.w};
#pragma unroll
            for (int j = 0; j < 8; ++j) {
                float x = xs[j] * iq;
                __bf16 h = (__bf16)x;
                aqh[ks][j] = h;
                aql[ks][j] = (__bf16)(x - (float)h);
            }
        }
    }

    // ---- pass 1: row sums of exp2(s' - SH), no barriers ----
    float lacc[4] = {0.f, 0.f, 0.f, 0.f};
    for (int kt = 0; kt < S_LEN; kt += KT) {
        int ncol = kt + wv * 16 + l16;
        f32x4 sv = qk_tile(kb + (size_t)ncol * DIM, klb + (size_t)ncol * DIM, aqh, aql, quad);
#pragma unroll
        for (int r = 0; r < 4; ++r) lacc[r] += exp2f(sv[r] - SH);
    }
#pragma unroll
    for (int r = 0; r < 4; ++r) {
#pragma unroll
        for (int off = 1; off < 16; off <<= 1) lacc[r] += __shfl_xor(lacc[r], off);
    }
    if (l16 == 0) {
#pragma unroll
        for (int r = 0; r < 4; ++r) redbuf[wv][quad * 4 + r] = lacc[r];
    }
    __syncthreads();
    if (tid < QT) {
        float l = redbuf[0][tid] + redbuf[1][tid] + redbuf[2][tid] + redbuf[3][tid];
        sinvl[tid] = 1.0f / l;
    }
    __syncthreads();

    float il[4];
#pragma unroll
    for (int r = 0; r < 4; ++r) il[r] = sinvl[quad * 4 + r];

    // ---- pass 2: recompute s, write score, accumulate O = P.V ----
    f32x4 o0 = {0.f, 0.f, 0.f, 0.f}, o1 = {0.f, 0.f, 0.f, 0.f};
    float* srow = scoreg + (size_t)bh * S_LEN * S_LEN;
    const int srow_r = tid >> 4, srow_c = tid & 15;   // for coalesced score write

    for (int kt = 0; kt < S_LEN; kt += KT) {
        int ncol = kt + wv * 16 + l16;
        f32x4 sv = qk_tile(kb + (size_t)ncol * DIM, klb + (size_t)ncol * DIM, aqh, aql, quad);
#pragma unroll
        for (int r = 0; r < 4; ++r) {
            float p = exp2f(sv[r] - SH) * il[r];
            pstage[(quad * 4 + r) * 68 + wv * 16 + l16] = p;   // C->A transpose via LDS
        }
        __syncthreads();
        // coalesced score write: 1 float4 per thread, 256B per 16-thread group
        {
            f32x4 p4 = *(const f32x4*)&pstage[srow_r * 68 + srow_c * 4];
            *(f32x4*)&srow[(size_t)(q0 + srow_r) * S_LEN + kt + srow_c * 4] = p4;
        }
        // P.V: A = p (m=l16, k=quad*8+j), B = v^T direct global loads
        const __bf16* vh = vtb  + (size_t)(wv * 16 + l16) * S_LEN + kt;
        const __bf16* vl = vtlb + (size_t)(wv * 16 + l16) * S_LEN + kt;
#pragma unroll
        for (int ks = 0; ks < 2; ++ks) {
            const float* pp = &pstage[l16 * 68 + ks * 32 + quad * 8];
            bf16x8 ph, pl;
#pragma unroll
            for (int j = 0; j < 8; ++j) {
                float x = pp[j];
                __bf16 h = (__bf16)x;
                ph[j] = h;
                pl[j] = (__bf16)(x - (float)h);
            }
            bf16x8 wh = *(const bf16x8*)(vh + ks * 32 + quad * 8);
            bf16x8 wl = *(const bf16x8*)(vl + ks * 32 + quad * 8);
            if (ks == 0) {
                o0 = MFMA16(ph, wh, o0);
                o0 = MFMA16(ph, wl, o0);
                o0 = MFMA16(pl, wh, o0);
            } else {
                o1 = MFMA16(ph, wh, o1);
                o1 = MFMA16(ph, wl, o1);
                o1 = MFMA16(pl, wh, o1);
            }
        }
        __syncthreads();
    }

    f32x4 o = o0 + o1;
#pragma unroll
    for (int r = 0; r < 4; ++r)
        outg[hbase + (size_t)(q0 + quad * 4 + r) * DIM + wv * 16 + l16] = o[r];
}

extern "C" void kernel_launch(void* const* d_in, const int* in_sizes, int n_in,
                              void* d_out, int out_size, void* d_ws, size_t ws_size,
                              hipStream_t stream) {
    const float* q = (const float*)d_in[0];
    const float* k = (const float*)d_in[1];
    const float* v = (const float*)d_in[2];
    float* out   = (float*)d_out;
    float* score = out + (size_t)NBH * S_LEN * DIM;

    const size_t NE = (size_t)NBH * S_LEN * DIM;  // 4M elements
    __bf16* khi  = (__bf16*)d_ws;                 // 8 MB each, 32 MB total
    __bf16* klo  = khi + NE;
    __bf16* vthi = klo + NE;
    __bf16* vtlo = vthi + NE;

    kprep_kernel<<<dim3(NBH * S_LEN / 4), 256, 0, stream>>>(k, khi, klo);
    vtprep_kernel<<<dim3(S_LEN / 64, NBH), 256, 0, stream>>>(v, vthi, vtlo);
    attn_kernel<<<dim3(S_LEN / QT, NBH), 256, 0, stream>>>(q, khi, klo, vthi, vtlo, out, score);
}